// Round 9
// baseline (38.654 us; speedup 1.0000x reference)
//
#include <hip/hip_runtime.h>

#define HH 1024
#define WW 1024
#define NIMG 8
#define TROWS 16            // output rows per block

__device__ __forceinline__ float med3f(float a, float b, float c) {
    return __builtin_amdgcn_fmed3f(a, b, c);
}
__device__ __forceinline__ float min3f(float a, float b, float c) {
    return fminf(fminf(a, b), c);
}
__device__ __forceinline__ float max3f(float a, float b, float c) {
    return fmaxf(fmaxf(a, b), c);
}

// ranks 3,4 of 5
__device__ __forceinline__ void top2(float a, float b, float c, float d, float e,
                                     float& r3, float& r4) {
    float m3 = med3f(a, b, c);
    float h3 = max3f(a, b, c);
    float s2 = med3f(m3, h3, d);
    float s3 = fmaxf(h3, d);
    r3 = med3f(s2, s3, e);
    r4 = fmaxf(s3, e);
}
// ranks 0,1 of 5
__device__ __forceinline__ void bot2(float a, float b, float c, float d, float e,
                                     float& r0, float& r1) {
    float l3 = min3f(a, b, c);
    float m3 = med3f(a, b, c);
    float s0 = fminf(l3, d);
    float s1 = med3f(l3, m3, d);
    r0 = fminf(s0, e);
    r1 = med3f(s0, s1, e);
}
// ranks 2,3,4 of 5
__device__ __forceinline__ void top3(float a, float b, float c, float d, float e,
                                     float& r2, float& r3, float& r4) {
    float l3 = min3f(a, b, c);
    float m3 = med3f(a, b, c);
    float h3 = max3f(a, b, c);
    float s1 = med3f(l3, m3, d);
    float s2 = med3f(m3, h3, d);
    float s3 = fmaxf(h3, d);
    r2 = med3f(s1, s2, e);
    r3 = med3f(s2, s3, e);
    r4 = fmaxf(s3, e);
}
// ranks 0,1,2 of 5
__device__ __forceinline__ void bot3(float a, float b, float c, float d, float e,
                                     float& r0, float& r1, float& r2) {
    float l3 = min3f(a, b, c);
    float m3 = med3f(a, b, c);
    float h3 = max3f(a, b, c);
    float s0 = fminf(l3, d);
    float s1 = med3f(l3, m3, d);
    float s2 = med3f(m3, h3, d);
    r0 = fminf(s0, e);
    r1 = med3f(s0, s1, e);
    r2 = med3f(s1, s2, e);
}
// ranks 1,2,3 of 5
__device__ __forceinline__ void mid3(float a, float b, float c, float d, float e,
                                     float& r1, float& r2, float& r3) {
    float l3 = min3f(a, b, c);
    float m3 = med3f(a, b, c);
    float h3 = max3f(a, b, c);
    float s0 = fminf(l3, d);
    float s1 = med3f(l3, m3, d);
    float s2 = med3f(m3, h3, d);
    float s3 = fmaxf(h3, d);
    r1 = med3f(s0, s1, e);
    r2 = med3f(s1, s2, e);
    r3 = med3f(s2, s3, e);
}

// load one reflect-padded input row (x handled branchlessly per-lane)
__device__ __forceinline__ void loadrow(const float* __restrict__ base, int r,
                                        int tid, int x0, float (&d)[8]) {
    const int rr = (r < 0) ? -r : (r >= HH ? 2 * HH - 2 - r : r);
    const float* rp = base + (size_t)rr * WW;
    const float4 A = *reinterpret_cast<const float4*>(rp + (tid == 0   ? x0 : x0 - 4));
    const float4 B = *reinterpret_cast<const float4*>(rp + x0);
    const float4 C = *reinterpret_cast<const float4*>(rp + (tid == 255 ? x0 : x0 + 4));
    d[0] = (tid == 0)   ? B.z : A.z;   // reflect(-2)=2, reflect(-1)=1
    d[1] = (tid == 0)   ? B.y : A.w;
    d[2] = B.x; d[3] = B.y; d[4] = B.z; d[5] = B.w;
    d[6] = (tid == 255) ? B.z : C.x;   // reflect(1024)=1022, reflect(1025)=1021
    d[7] = (tid == 255) ? B.y : C.y;
}

// 13-candidate exact median-of-25 network over sorted columns (validated R2-R8)
__device__ __forceinline__ void med4net(const float (&S0)[8], const float (&S1)[8],
                                        const float (&S2)[8], const float (&S3)[8],
                                        const float (&S4)[8], float (&med)[4]) {
    #pragma unroll
    for (int j = 0; j < 4; ++j) {
        float r03, r04, r12, r13, r14, r21, r22, r23, r30, r31, r32, r40, r41;
        top2(S0[j], S0[j+1], S0[j+2], S0[j+3], S0[j+4], r03, r04);
        top3(S1[j], S1[j+1], S1[j+2], S1[j+3], S1[j+4], r12, r13, r14);
        mid3(S2[j], S2[j+1], S2[j+2], S2[j+3], S2[j+4], r21, r22, r23);
        bot3(S3[j], S3[j+1], S3[j+2], S3[j+3], S3[j+4], r30, r31, r32);
        bot2(S4[j], S4[j+1], S4[j+2], S4[j+3], S4[j+4], r40, r41);
        float u = fminf(r40, r31), v = fmaxf(r40, r31);
        float w = fminf(v, r32),  x = fmaxf(v, r32);
        float ps0 = r30, ps1 = u, ps2 = w;
        float ps3 = fminf(x, r41), ps4 = fmaxf(x, r41);
        float q0 = fminf(r21, r03);
        float q1 = med3f(r21, r22, r03);
        float q2 = med3f(r22, r23, r03);
        float t1 = fminf(q1, r04);
        float t2 = med3f(q1, q2, r04);
        float t3 = med3f(q2, r23, r04);
        float t4 = fmaxf(r23, r04);
        float Y0 = fmaxf(ps0, q0);
        float Y1 = fmaxf(ps1, t1);
        float X2 = fminf(ps2, t2), Y2 = fmaxf(ps2, t2);
        float X3 = fminf(ps3, t3);
        float X4 = fminf(ps4, t4);
        float L  = max3f(X2, Y0, r12);
        float M  = med3f(X3, Y1, r13);
        float Hc = min3f(X4, Y2, r14);
        med[j] = med3f(L, M, Hc);
    }
}

// Median pair-step P (0..9): med rows m0 = y0-2+2P, m0+1 via shared sorted4.
// Results -> register ring medr[2*(P%5)], [2*(P%5)+1]. Seam lanes (0,63)
// export 4 scalars/row to the tiny LDS seam buffer. No barrier here.
template<int P>
__device__ __forceinline__ void pairstep(int y0, int tid, int x0, int lane, int w,
                                         const float* __restrict__ base,
                                         float (&ring)[8][8], float (&medr)[10][4],
                                         float (*seam)[4][10][4]) {
    constexpr int B  = P / 5;          // seam buffer (batch)
    constexpr int RR = 2 * (P % 5);    // medr row base
    // prefetch next two input rows
    if constexpr (P <= 8) {
        loadrow(base, y0 + 2 + 2 * P, tid, x0, ring[(2 * P + 6) & 7]);
        loadrow(base, y0 + 3 + 2 * P, tid, x0, ring[(2 * P + 7) & 7]);
    }
    constexpr int s0 = (2*P) & 7,     s1 = (2*P + 1) & 7, s2 = (2*P + 2) & 7;
    constexpr int s3 = (2*P + 3) & 7, s4 = (2*P + 4) & 7, s5 = (2*P + 5) & 7;
    float T0[8], T1[8], T2[8], T3[8];  // sorted4 of the 4 shared rows
    #pragma unroll
    for (int c = 0; c < 8; ++c) {
        float b = ring[s1][c], cc = ring[s2][c], d = ring[s3][c], e = ring[s4][c];
        float l3 = min3f(b, cc, d);
        float m3 = med3f(b, cc, d);
        float h3 = max3f(b, cc, d);
        T0[c] = fminf(l3, e);
        T1[c] = med3f(l3, m3, e);
        T2[c] = med3f(m3, h3, e);
        T3[c] = fmaxf(h3, e);
    }
    const int m0 = y0 - 2 + 2 * P;
    float med0[4] = {0.f, 0.f, 0.f, 0.f};
    float med1[4] = {0.f, 0.f, 0.f, 0.f};
    if (m0 >= 0 && m0 < HH) {          // insert row m0-2 (slot s0)
        float S0[8], S1[8], S2[8], S3[8], S4[8];
        #pragma unroll
        for (int c = 0; c < 8; ++c) {
            float a = ring[s0][c];
            S0[c] = fminf(T0[c], a);
            S1[c] = med3f(T0[c], T1[c], a);
            S2[c] = med3f(T1[c], T2[c], a);
            S3[c] = med3f(T2[c], T3[c], a);
            S4[c] = fmaxf(T3[c], a);
        }
        med4net(S0, S1, S2, S3, S4, med0);
    }
    if (m0 + 1 >= 0 && m0 + 1 < HH) {  // insert row m1+2 (slot s5)
        float S0[8], S1[8], S2[8], S3[8], S4[8];
        #pragma unroll
        for (int c = 0; c < 8; ++c) {
            float f = ring[s5][c];
            S0[c] = fminf(T0[c], f);
            S1[c] = med3f(T0[c], T1[c], f);
            S2[c] = med3f(T1[c], T2[c], f);
            S3[c] = med3f(T2[c], T3[c], f);
            S4[c] = fmaxf(T3[c], f);
        }
        med4net(S0, S1, S2, S3, S4, med1);
    }
    #pragma unroll
    for (int j = 0; j < 4; ++j) { medr[RR][j] = med0[j]; medr[RR + 1][j] = med1[j]; }
    // seam export: lane 0 gives meds[0,1] (for left neighbor wave's lane 63),
    // lane 63 gives meds[2,3] (for right neighbor wave's lane 0).
    if (lane == 0 || lane == 63) {
        const int off = (lane == 0) ? 0 : 2;
        float e00 = (lane == 0) ? med0[0] : med0[2];
        float e01 = (lane == 0) ? med0[1] : med0[3];
        float e10 = (lane == 0) ? med1[0] : med1[2];
        float e11 = (lane == 0) ? med1[1] : med1[3];
        *reinterpret_cast<float2*>(&seam[B][w][RR][off])     = make_float2(e00, e01);
        *reinterpret_cast<float2*>(&seam[B][w][RR + 1][off]) = make_float2(e10, e11);
    }
}

// Gauss batch B (0/1): consumes medr rows 0..9 (med rows y0-2+10B .. +9),
// x-halo via register shuffles + seam LDS fix at wave boundaries,
// h-gauss -> hr ring, v-gauss + store.
template<int B>
__device__ __forceinline__ void gaussbatch(int y0, int x0, int lane, int w,
                                           float* __restrict__ obase,
                                           const float (&wv)[5],
                                           const float (&medr)[10][4],
                                           float (&hr)[6][4],
                                           const float (*seam)[4][10][4]) {
    #pragma unroll
    for (int r = 0; r < 10; ++r) {
        const int m = y0 - 2 + 10 * B + r;
        const float m0 = medr[r][0], m1 = medr[r][1];
        const float m2 = medr[r][2], m3 = medr[r][3];
        // neighbors via wave shuffles (px x0-2, x0-1 from lane-1; x0+4, x0+5 from lane+1)
        float ml0 = __shfl_up(m2, 1);
        float ml1 = __shfl_up(m3, 1);
        float mr0 = __shfl_down(m0, 1);
        float mr1 = __shfl_down(m1, 1);
        if (lane == 0) {            // wave seam / image edge
            if (w > 0) {
                float2 t = *reinterpret_cast<const float2*>(&seam[B][w - 1][r][2]);
                ml0 = t.x; ml1 = t.y;
            } else { ml0 = 0.f; ml1 = 0.f; }
        }
        if (lane == 63) {
            if (w < 3) {
                float2 t = *reinterpret_cast<const float2*>(&seam[B][w + 1][r][0]);
                mr0 = t.x; mr1 = t.y;
            } else { mr0 = 0.f; mr1 = 0.f; }
        }
        const float hh[8] = { ml0, ml1, m0, m1, m2, m3, mr0, mr1 };
        #pragma unroll
        for (int j = 0; j < 4; ++j) {
            float h = 0.f;
            #pragma unroll
            for (int c = 0; c < 5; ++c) h = fmaf(wv[c], hh[j + c], h);
            hr[(10 * B + r) % 6][j] = h;
        }
        if (10 * B + r >= 4) {      // v-gauss + store output row o = m-2
            const int o = m - 2;
            float a0 = 0.f, a1 = 0.f, a2 = 0.f, a3 = 0.f;
            #pragma unroll
            for (int k = 0; k < 5; ++k) {
                const int   sl = (10 * B + r - 4 + k) % 6;
                const float wy = wv[k];
                a0 = fmaf(wy, hr[sl][0], a0);
                a1 = fmaf(wy, hr[sl][1], a1);
                a2 = fmaf(wy, hr[sl][2], a2);
                a3 = fmaf(wy, hr[sl][3], a3);
            }
            *reinterpret_cast<float4*>(obase + (size_t)o * WW + x0) =
                make_float4(a0, a1, a2, a3);
        }
    }
}

// Fused median(reflect) + gaussian(zero-pad). Block = 16 rows x 1024 px.
// img = bid & 7 -> XCD-affine. 2 barriers per block (vs 10 in R8): median
// pairs accumulate 10 rows in a register ring; x-halo via shuffles; only
// 4 scalars/row/wave cross wave boundaries through a 1.3 KB LDS seam buffer.
__global__ __launch_bounds__(256, 2) void fused_kernel(const float* __restrict__ in,
                                                       const float* __restrict__ sig,
                                                       float* __restrict__ out) {
    const int bi   = blockIdx.x;
    const int img  = bi & 7;
    const int tile = bi >> 3;
    const int y0   = tile * TROWS;
    const int tid  = threadIdx.x;
    const int x0   = tid * 4;
    const int lane = tid & 63;
    const int w    = tid >> 6;
    const float* base  = in  + (size_t)img * HH * WW;
    float*       obase = out + (size_t)img * HH * WW;

    const float sigma  = sig[0];
    const float inv2s2 = 1.0f / (2.0f * sigma * sigma);
    const float g1 = expf(-1.0f * inv2s2);
    const float g4 = expf(-4.0f * inv2s2);
    const float sn = 1.0f + 2.0f * g1 + 2.0f * g4;
    const float wv[5] = { g4 / sn, g1 / sn, 1.0f / sn, g1 / sn, g4 / sn };

    __shared__ float seam[2][4][10][4];   // [batch][wave][row][4]

    float ring[8][8];    // raw input rows; row r <-> slot (r - y0 + 4) & 7
    float medr[10][4];   // batch of 10 median rows (registers)
    float hr[6][4];      // h-blurred med rows ring

    #pragma unroll
    for (int k = 0; k < 6; ++k) loadrow(base, y0 - 4 + k, tid, x0, ring[k]);

    // batch 0: median rows y0-2 .. y0+7
    pairstep<0>(y0, tid, x0, lane, w, base, ring, medr, seam);
    pairstep<1>(y0, tid, x0, lane, w, base, ring, medr, seam);
    pairstep<2>(y0, tid, x0, lane, w, base, ring, medr, seam);
    pairstep<3>(y0, tid, x0, lane, w, base, ring, medr, seam);
    pairstep<4>(y0, tid, x0, lane, w, base, ring, medr, seam);
    __syncthreads();
    gaussbatch<0>(y0, x0, lane, w, obase, wv, medr, hr, seam);  // outputs y0..y0+5
    // batch 1: median rows y0+8 .. y0+17 (can co-schedule with gaussbatch<0>)
    pairstep<5>(y0, tid, x0, lane, w, base, ring, medr, seam);
    pairstep<6>(y0, tid, x0, lane, w, base, ring, medr, seam);
    pairstep<7>(y0, tid, x0, lane, w, base, ring, medr, seam);
    pairstep<8>(y0, tid, x0, lane, w, base, ring, medr, seam);
    pairstep<9>(y0, tid, x0, lane, w, base, ring, medr, seam);
    __syncthreads();
    gaussbatch<1>(y0, x0, lane, w, obase, wv, medr, hr, seam);  // outputs y0+6..y0+15
}

extern "C" void kernel_launch(void* const* d_in, const int* in_sizes, int n_in,
                              void* d_out, int out_size, void* d_ws, size_t ws_size,
                              hipStream_t stream) {
    const float* img = (const float*)d_in[0];
    const float* sig = (const float*)d_in[1];
    float* out = (float*)d_out;

    dim3 grid(NIMG * (HH / TROWS));  // 512 blocks, XCD-affine via bid&7
    dim3 block(256);
    hipLaunchKernelGGL(fused_kernel, grid, block, 0, stream, img, sig, out);
}